// Round 18
// baseline (122.694 us; speedup 1.0000x reference)
//
#include <hip/hip_runtime.h>
#include <math.h>

// FinalGNN: b=16, n=256, feature=64
// ws layout (floats):
#define OFF_H      0                    // h    [4096][64] row-major
#define OFF_AI     262144               // a_i  [4096][64] (includes s_b1)
#define OFF_AJH    524288               // ajh  [16][64][256][2]  {a_j, h} interleaved
#define OFF_SAI    1048576              // per-row scalars, 4096 each
#define OFF_QAI    1052672
#define OFF_SAJ    1056768
#define OFF_QAJ    1060864
#define OFF_SQH    1064960
#define OFF_HRES   1069056              // h_res [4096][64]
#define OFF_SYNC   1331200              // counter, flag (2 uints)

// fast transcendentals (native HW exp/log; ~2-4 ulp, fine vs 5.25e-2 threshold)
__device__ __forceinline__ float fexp(float x)  { return __expf(x); }
__device__ __forceinline__ float flog(float x)  { return __logf(x); }
__device__ __forceinline__ float frcp(float x)  {
    float r = __builtin_amdgcn_rcpf(x);
    return r * (2.f - x * r);            // 1 Newton step
}
__device__ __forceinline__ float frsq(float x)  { return __builtin_amdgcn_rsqf(x); }
__device__ __forceinline__ float elu_f(float x) { return x > 0.f ? x : fexp(x) - 1.f; }
__device__ __forceinline__ float softplus_f(float x) {
    return fmaxf(x, 0.f) + flog(1.f + fexp(-fabsf(x)));
}

// K1: embed + scalars; also resets the k2 sync cells (stream-ordered before k2).
__global__ __launch_bounds__(256) void k1_embed(
    const float* __restrict__ x,
    const float* __restrict__ proj_w, const float* __restrict__ proj_b,
    const float* __restrict__ s_w1, const float* __restrict__ s_b1,
    float* __restrict__ h, float* __restrict__ a_i, float2* __restrict__ ajh,
    float* __restrict__ sa_i, float* __restrict__ qa_i,
    float* __restrict__ sa_j, float* __restrict__ qa_j,
    float* __restrict__ sqh, unsigned* __restrict__ sync)
{
    if (blockIdx.x == 0 && threadIdx.x == 0) { sync[0] = 0u; sync[1] = 0u; }

    __shared__ float w_sh[8192];   // s_w1 [128][64]
    int tid = threadIdx.x;
    #pragma unroll
    for (int r = 0; r < 8; ++r)
        *(float4*)&w_sh[(r*256 + tid)*4] = *(const float4*)&s_w1[(r*256 + tid)*4];
    __syncthreads();

    int lane = tid & 63;
    int wave = tid >> 6;
    int row0 = blockIdx.x * 8;

    float pw0 = proj_w[lane], pw1 = proj_w[64+lane], pw2 = proj_w[128+lane],
          pw3 = proj_w[192+lane], pb = proj_b[lane], b1 = s_b1[lane];

    #pragma unroll
    for (int r = 0; r < 2; ++r) {
        int row = row0 + wave*2 + r;          // b*256 + i
        int b = row >> 8, i = row & 255;
        float4 xv = *(const float4*)&x[row*4];
        float hv = elu_f(xv.x*pw0 + xv.y*pw1 + xv.z*pw2 + xv.w*pw3 + pb);

        float ai = b1, aj = 0.f;
        #pragma unroll 8
        for (int e = 0; e < 64; ++e) {
            float he = __shfl(hv, e);
            ai = fmaf(he, w_sh[e*64 + lane], ai);
            aj = fmaf(he, w_sh[(64+e)*64 + lane], aj);
        }
        h[row*64 + lane]   = hv;
        a_i[row*64 + lane] = ai;
        ajh[b*16384 + lane*256 + i] = make_float2(aj, hv);

        float v1 = ai, v2 = ai*ai, v3 = aj, v4 = aj*aj, v5 = hv*hv;
        #pragma unroll
        for (int off = 32; off > 0; off >>= 1) {
            v1 += __shfl_xor(v1, off);
            v2 += __shfl_xor(v2, off);
            v3 += __shfl_xor(v3, off);
            v4 += __shfl_xor(v4, off);
            v5 += __shfl_xor(v5, off);
        }
        if (lane == 0) {
            sa_i[row] = v1; qa_i[row] = v2;
            sa_j[row] = v3; qa_j[row] = v4;
            sqh[row]  = v5;
        }
    }
}

// K2: R16 pair kernel + fused phase D via last-16-arrivals ticket scheme.
// 1024 blocks x 256 threads; block = (b, 4-i tile), thread = j.
__global__ __launch_bounds__(256) void k2_pair(
    const float* __restrict__ a_i, const float2* __restrict__ ajh,
    const float* __restrict__ h,
    const float* __restrict__ sa_i, const float* __restrict__ qa_i,
    const float* __restrict__ sa_j, const float* __restrict__ qa_j,
    const float* __restrict__ sqh,
    const float* __restrict__ ln_g, const float* __restrict__ ln_b,
    const float* __restrict__ s_w2, const float* __restrict__ s_b2,
    const float* __restrict__ gnn_w,
    const float* __restrict__ c_w1, const float* __restrict__ c_b1,
    const float* __restrict__ bn_g, const float* __restrict__ bn_b,
    const float* __restrict__ bn_mean, const float* __restrict__ bn_var,
    const float* __restrict__ c_w2, const float* __restrict__ c_b2,
    float* __restrict__ h_res, unsigned* __restrict__ sync,
    float* __restrict__ out)
{
    int bi0 = blockIdx.x * 4;          // first row (b*256 + i0)
    int b   = bi0 >> 8;
    int j   = threadIdx.x;
    int gj  = b*256 + j;

    __shared__ float aiT[64][4], hiT[64][4];   // [d][i]
    __shared__ float gbw[64][4];               // {ln_g, ln_b, s_w2, 0}
    __shared__ float sai_s[4], qai_s[4], sqi_s[4];
    __shared__ float adj_sh[256][4];           // [j][i]
    __shared__ float pool[16*4*64];            // agg partials [16][4][64]
    __shared__ float hagg_sh[4][64];
    __shared__ unsigned arrival;

    {
        int i = j >> 6, d = j & 63;
        aiT[d][i] = a_i[(bi0+i)*64 + d];
        hiT[d][i] = h[(bi0+i)*64 + d];
    }
    if (j < 64) {
        gbw[j][0] = ln_g[j]; gbw[j][1] = ln_b[j]; gbw[j][2] = s_w2[j]; gbw[j][3] = 0.f;
    }
    if (j < 4) {
        sai_s[j] = sa_i[bi0+j]; qai_s[j] = qa_i[bi0+j]; sqi_s[j] = sqh[bi0+j];
    }
    float saj = sa_j[gj], qaj = qa_j[gj], sqj = sqh[gj];
    float b2  = s_b2[0];
    __syncthreads();

    const float2* ajhb = ajh + b*16384;        // [d][j] of {a_j, h}

    // ---- pass 1: grams from single float2 stream ----
    float ga[4] = {0.f,0.f,0.f,0.f}, gh[4] = {0.f,0.f,0.f,0.f};
    #pragma unroll 8
    for (int d = 0; d < 64; ++d) {
        float2 v = ajhb[d*256 + j];
        float4 A = *(const float4*)&aiT[d][0];
        float4 H = *(const float4*)&hiT[d][0];
        ga[0] = fmaf(A.x, v.x, ga[0]); ga[1] = fmaf(A.y, v.x, ga[1]);
        ga[2] = fmaf(A.z, v.x, ga[2]); ga[3] = fmaf(A.w, v.x, ga[3]);
        gh[0] = fmaf(H.x, v.y, gh[0]); gh[1] = fmaf(H.y, v.y, gh[1]);
        gh[2] = fmaf(H.z, v.y, gh[2]); gh[3] = fmaf(H.w, v.y, gh[3]);
    }

    // ---- LN stats from scalar decomposition (fast rsqrt) ----
    float rs4[4], nr4[4], d24[4];
    #pragma unroll
    for (int i = 0; i < 4; ++i) {
        float mu  = (sai_s[i] + saj) * (1.f/64.f);
        float pss = qai_s[i] + qaj + 2.f*ga[i];
        float var = pss * (1.f/64.f) - mu*mu;
        rs4[i] = frsq(var + 1e-5f);
        nr4[i] = -mu * rs4[i];
        d24[i] = fmaxf(sqi_s[i] + sqj - 2.f*gh[i], 0.f);
    }

    // ---- pass 2: reread float2 (cache-hot), LN -> relu -> dot(w2) ----
    float acc[4] = {0.f,0.f,0.f,0.f};
    #pragma unroll 8
    for (int d = 0; d < 64; ++d) {
        float ajd = ajhb[d*256 + j].x;
        float4 A = *(const float4*)&aiT[d][0];
        float4 G = *(const float4*)&gbw[d][0];
        float t0 = fmaxf(fmaf(fmaf(A.x + ajd, rs4[0], nr4[0]), G.x, G.y), 0.f);
        acc[0] = fmaf(t0, G.z, acc[0]);
        float t1 = fmaxf(fmaf(fmaf(A.y + ajd, rs4[1], nr4[1]), G.x, G.y), 0.f);
        acc[1] = fmaf(t1, G.z, acc[1]);
        float t2 = fmaxf(fmaf(fmaf(A.z + ajd, rs4[2], nr4[2]), G.x, G.y), 0.f);
        acc[2] = fmaf(t2, G.z, acc[2]);
        float t3 = fmaxf(fmaf(fmaf(A.w + ajd, rs4[3], nr4[3]), G.x, G.y), 0.f);
        acc[3] = fmaf(t3, G.z, acc[3]);
    }

    // ---- sigma, adj (fast exp/log/rcp) ----
    {
        float4 av;
        #pragma unroll
        for (int i = 0; i < 4; ++i) {
            float sig = softplus_f(acc[i] + b2);
            float inv = frcp(2.f*sig*sig + 1e-6f);
            ((float*)&av)[i] = fexp(-d24[i] * inv);
        }
        *(float4*)&adj_sh[j][0] = av;
    }
    __syncthreads();

    // ---- aggregation: float4 loads, 16-lane-group mapping ----
    {
        int q = j >> 4, dq = j & 15;
        const float* hb = h + b*256*64;
        float4 p0 = {0.f,0.f,0.f,0.f}, p1 = p0, p2 = p0, p3 = p0;
        #pragma unroll
        for (int k = 0; k < 16; ++k) {
            int jj = q*16 + k;
            float4 hv = *(const float4*)&hb[jj*64 + dq*4];
            float4 a4 = *(const float4*)&adj_sh[jj][0];
            p0.x=fmaf(a4.x,hv.x,p0.x); p0.y=fmaf(a4.x,hv.y,p0.y);
            p0.z=fmaf(a4.x,hv.z,p0.z); p0.w=fmaf(a4.x,hv.w,p0.w);
            p1.x=fmaf(a4.y,hv.x,p1.x); p1.y=fmaf(a4.y,hv.y,p1.y);
            p1.z=fmaf(a4.y,hv.z,p1.z); p1.w=fmaf(a4.y,hv.w,p1.w);
            p2.x=fmaf(a4.z,hv.x,p2.x); p2.y=fmaf(a4.z,hv.y,p2.y);
            p2.z=fmaf(a4.z,hv.z,p2.z); p2.w=fmaf(a4.z,hv.w,p2.w);
            p3.x=fmaf(a4.w,hv.x,p3.x); p3.y=fmaf(a4.w,hv.y,p3.y);
            p3.z=fmaf(a4.w,hv.z,p3.z); p3.w=fmaf(a4.w,hv.w,p3.w);
        }
        *(float4*)&pool[(q*4 + 0)*64 + dq*4] = p0;
        *(float4*)&pool[(q*4 + 1)*64 + dq*4] = p1;
        *(float4*)&pool[(q*4 + 2)*64 + dq*4] = p2;
        *(float4*)&pool[(q*4 + 3)*64 + dq*4] = p3;
    }
    __syncthreads();

    {
        int i = j >> 6, d = j & 63;
        float s = 0.f;
        #pragma unroll
        for (int q2 = 0; q2 < 16; ++q2)
            s += pool[(q2*4 + i)*64 + d];
        hagg_sh[i][d] = s;
    }
    __syncthreads();

    // ---- fused gnn: h_res = elu(hagg @ gnn_w + h) ----
    {
        int i = j >> 6, lane = j & 63;
        float accg = 0.f;
        #pragma unroll 8
        for (int e = 0; e < 64; ++e)
            accg = fmaf(hagg_sh[i][e], gnn_w[e*64 + lane], accg);
        h_res[(bi0+i)*64 + lane] = elu_f(accg + hiT[lane][i]);
    }

    // ================= fused phase D: last-16-arrivals do pool+classifier =====
    __threadfence();                           // h_res visible device-wide
    if (j == 0) arrival = atomicAdd(&sync[0], 1u);
    __syncthreads();
    unsigned a = arrival;
    if (a < 1008u) return;
    int bb = (int)(a - 1008u);                 // 0..15, one batch per late block

    if (j == 0) {
        if (a == 1023u) {
            atomicExch(&sync[1], 1u);          // all 1024 arrived -> release
        } else {
            while (atomicAdd(&sync[1], 0u) == 0u)
                __builtin_amdgcn_s_sleep(8);   // spinner is resident by definition
        }
    }
    __syncthreads();
    __threadfence();                           // acquire h_res

    {
        // reuse pool as: sum[256] max[256] pm[64] px[64]
        float* sum_sh = pool;
        float* max_sh = pool + 256;
        float* pm_sh  = pool + 512;
        float* px_sh  = pool + 576;

        int d = j & 63, q = j >> 6;
        const float* hb = h_res + bb*256*64;

        float sum = 0.f, mx = -INFINITY;
        #pragma unroll 8
        for (int k = 0; k < 64; ++k) {
            float v = hb[(q*64+k)*64 + d];
            sum += v; mx = fmaxf(mx, v);
        }
        sum_sh[j] = sum; max_sh[j] = mx;
        __syncthreads();
        if (j < 64) {
            float tsum = sum_sh[j] + sum_sh[64+j] + sum_sh[128+j] + sum_sh[192+j];
            float tmax = fmaxf(fmaxf(max_sh[j], max_sh[64+j]),
                               fmaxf(max_sh[128+j], max_sh[192+j]));
            pm_sh[j] = tsum * (1.f/256.f);
            px_sh[j] = tmax;
        }
        __syncthreads();
        if (j < 64) {
            float acc2 = c_b1[j];
            #pragma unroll
            for (int e = 0; e < 64; ++e) {
                acc2 += pm_sh[e] * c_w1[e*64 + j];
                acc2 += px_sh[e] * c_w1[(64+e)*64 + j];
            }
            float z = (acc2 - bn_mean[j]) * rsqrtf(bn_var[j] + 1e-5f) * bn_g[j] + bn_b[j];
            z = elu_f(z);
            float c0 = z * c_w2[j*2 + 0];
            float c1 = z * c_w2[j*2 + 1];
            for (int off = 32; off > 0; off >>= 1) {
                c0 += __shfl_down(c0, off);
                c1 += __shfl_down(c1, off);
            }
            if (j == 0) {
                out[bb*2 + 0] = c0 + c_b2[0];
                out[bb*2 + 1] = c1 + c_b2[1];
            }
        }
    }
}

extern "C" void kernel_launch(void* const* d_in, const int* in_sizes, int n_in,
                              void* d_out, int out_size, void* d_ws, size_t ws_size,
                              hipStream_t stream) {
    const float* x       = (const float*)d_in[0];
    const float* proj_w  = (const float*)d_in[1];
    const float* proj_b  = (const float*)d_in[2];
    const float* s_w1    = (const float*)d_in[3];
    const float* s_b1    = (const float*)d_in[4];
    const float* ln_g    = (const float*)d_in[5];
    const float* ln_b    = (const float*)d_in[6];
    const float* s_w2    = (const float*)d_in[7];
    const float* s_b2    = (const float*)d_in[8];
    const float* gnn_w   = (const float*)d_in[9];
    const float* c_w1    = (const float*)d_in[10];
    const float* c_b1    = (const float*)d_in[11];
    const float* bn_g    = (const float*)d_in[12];
    const float* bn_b    = (const float*)d_in[13];
    const float* bn_mean = (const float*)d_in[14];
    const float* bn_var  = (const float*)d_in[15];
    const float* c_w2    = (const float*)d_in[16];
    const float* c_b2    = (const float*)d_in[17];

    float* w = (float*)d_ws;
    float*    h     = w + OFF_H;
    float*    a_i   = w + OFF_AI;
    float2*   ajh   = (float2*)(w + OFF_AJH);
    float*    sa_i  = w + OFF_SAI;
    float*    qa_i  = w + OFF_QAI;
    float*    sa_j  = w + OFF_SAJ;
    float*    qa_j  = w + OFF_QAJ;
    float*    sqh   = w + OFF_SQH;
    float*    h_res = w + OFF_HRES;
    unsigned* sync  = (unsigned*)(w + OFF_SYNC);
    float*    out   = (float*)d_out;

    k1_embed<<<512, 256, 0, stream>>>(x, proj_w, proj_b, s_w1, s_b1,
                                      h, a_i, ajh,
                                      sa_i, qa_i, sa_j, qa_j, sqh, sync);
    k2_pair<<<1024, 256, 0, stream>>>(a_i, ajh, h,
                                      sa_i, qa_i, sa_j, qa_j, sqh,
                                      ln_g, ln_b, s_w2, s_b2, gnn_w,
                                      c_w1, c_b1, bn_g, bn_b, bn_mean, bn_var,
                                      c_w2, c_b2, h_res, sync, out);
}

// Round 19
// 47.223 us; speedup vs baseline: 2.5982x; 2.5982x over previous
//
#include <hip/hip_runtime.h>
#include <math.h>

// FinalGNN: b=16, n=256, feature=64
// ws layout (floats):
#define OFF_H      0                    // h    [4096][64] row-major
#define OFF_AI     262144               // a_i  [4096][64] (includes s_b1)
#define OFF_AJH    524288               // ajh  [16][64][256][2]  {a_j, h}
#define OFF_SAI    1048576              // per-row scalars, 4096 each
#define OFF_QAI    1052672
#define OFF_SAJ    1056768
#define OFF_QAJ    1060864
#define OFF_SQH    1064960
#define OFF_GA     1069056              // ga [4096][256]
#define OFF_GH     2117632              // gh [4096][256]
#define OFF_HRES   3166208              // h_res [4096][64]
#define OFF_BF     3428352              // 3 bf16 arrays (shorts) follow

typedef __attribute__((ext_vector_type(8))) short bf16x8;
typedef __attribute__((ext_vector_type(4))) float f32x4;

// fast transcendentals (native HW exp/log; ~2-4 ulp)
__device__ __forceinline__ float fexp(float x)  { return __expf(x); }
__device__ __forceinline__ float flog(float x)  { return __logf(x); }
__device__ __forceinline__ float frcp(float x)  {
    float r = __builtin_amdgcn_rcpf(x);
    return r * (2.f - x * r);
}
__device__ __forceinline__ float frsq(float x)  { return __builtin_amdgcn_rsqf(x); }
__device__ __forceinline__ float elu_f(float x) { return x > 0.f ? x : fexp(x) - 1.f; }
__device__ __forceinline__ float softplus_f(float x) {
    return fmaxf(x, 0.f) + flog(1.f + fexp(-fabsf(x)));
}
__device__ __forceinline__ short f2bf(float f) {
    unsigned u = __float_as_uint(f);
    unsigned r = (u + 0x7FFF + ((u >> 16) & 1)) >> 16;   // RNE
    return (short)r;
}

// K1: embed + scalars + bf16 copies for MFMA grams. 512 blocks x 256.
__global__ __launch_bounds__(256) void k1_embed(
    const float* __restrict__ x,
    const float* __restrict__ proj_w, const float* __restrict__ proj_b,
    const float* __restrict__ s_w1, const float* __restrict__ s_b1,
    float* __restrict__ h, float* __restrict__ a_i, float2* __restrict__ ajh,
    short* __restrict__ ai_bf, short* __restrict__ aj_bf, short* __restrict__ h_bf,
    float* __restrict__ sa_i, float* __restrict__ qa_i,
    float* __restrict__ sa_j, float* __restrict__ qa_j,
    float* __restrict__ sqh)
{
    __shared__ float w_sh[8192];   // s_w1 [128][64]
    int tid = threadIdx.x;
    #pragma unroll
    for (int r = 0; r < 8; ++r)
        *(float4*)&w_sh[(r*256 + tid)*4] = *(const float4*)&s_w1[(r*256 + tid)*4];
    __syncthreads();

    int lane = tid & 63;
    int wave = tid >> 6;
    int row0 = blockIdx.x * 8;

    float pw0 = proj_w[lane], pw1 = proj_w[64+lane], pw2 = proj_w[128+lane],
          pw3 = proj_w[192+lane], pb = proj_b[lane], b1 = s_b1[lane];

    #pragma unroll
    for (int r = 0; r < 2; ++r) {
        int row = row0 + wave*2 + r;          // b*256 + i
        int b = row >> 8, i = row & 255;
        float4 xv = *(const float4*)&x[row*4];
        float hv = elu_f(xv.x*pw0 + xv.y*pw1 + xv.z*pw2 + xv.w*pw3 + pb);

        float ai = b1, aj = 0.f;
        #pragma unroll 8
        for (int e = 0; e < 64; ++e) {
            float he = __shfl(hv, e);
            ai = fmaf(he, w_sh[e*64 + lane], ai);
            aj = fmaf(he, w_sh[(64+e)*64 + lane], aj);
        }
        h[row*64 + lane]   = hv;
        a_i[row*64 + lane] = ai;
        ajh[b*16384 + lane*256 + i] = make_float2(aj, hv);
        ai_bf[row*64 + lane] = f2bf(ai);
        aj_bf[row*64 + lane] = f2bf(aj);
        h_bf [row*64 + lane] = f2bf(hv);

        float v1 = ai, v2 = ai*ai, v3 = aj, v4 = aj*aj, v5 = hv*hv;
        #pragma unroll
        for (int off = 32; off > 0; off >>= 1) {
            v1 += __shfl_xor(v1, off);
            v2 += __shfl_xor(v2, off);
            v3 += __shfl_xor(v3, off);
            v4 += __shfl_xor(v4, off);
            v5 += __shfl_xor(v5, off);
        }
        if (lane == 0) {
            sa_i[row] = v1; qa_i[row] = v2;
            sa_j[row] = v3; qa_j[row] = v4;
            sqh[row]  = v5;
        }
    }
}

// KGRAM (validated R10): ga = Ai.Aj^T, gh = H.H^T via mfma_f32_16x16x32_bf16.
__global__ __launch_bounds__(64) void kgram(
    const short* __restrict__ ai_bf, const short* __restrict__ aj_bf,
    const short* __restrict__ h_bf,
    float* __restrict__ ga, float* __restrict__ gh)
{
    int bid = blockIdx.x;
    int g = bid & 1;
    int s = (bid >> 1) & 15;
    int b = bid >> 5;
    const short* XA = (g ? h_bf : ai_bf) + b*256*64;
    const short* XB = (g ? h_bf : aj_bf) + b*256*64;
    float* G = (g ? gh : ga) + (b*256 + s*16)*256;

    int l = threadIdx.x, lo = l & 15, hi = l >> 4;

    bf16x8 a0 = *(const bf16x8*)&XA[(s*16 + lo)*64 + hi*8];
    bf16x8 a1 = *(const bf16x8*)&XA[(s*16 + lo)*64 + 32 + hi*8];

    #pragma unroll 4
    for (int jt = 0; jt < 16; ++jt) {
        bf16x8 b0 = *(const bf16x8*)&XB[(jt*16 + lo)*64 + hi*8];
        bf16x8 b1 = *(const bf16x8*)&XB[(jt*16 + lo)*64 + 32 + hi*8];
        f32x4 c = {0.f, 0.f, 0.f, 0.f};
        c = __builtin_amdgcn_mfma_f32_16x16x32_bf16(a0, b0, c, 0, 0, 0);
        c = __builtin_amdgcn_mfma_f32_16x16x32_bf16(a1, b1, c, 0, 0, 0);
        #pragma unroll
        for (int r = 0; r < 4; ++r)
            G[(hi*4 + r)*256 + jt*16 + lo] = c[r];
    }
}

// K2: R16 structure with pass-1 DELETED (grams from kgram).
// 1024 blocks x 256 threads; block = (b, 4-i tile), thread = j.
__global__ __launch_bounds__(256) void k2_pair(
    const float* __restrict__ a_i, const float2* __restrict__ ajh,
    const float* __restrict__ h,
    const float* __restrict__ ga_m, const float* __restrict__ gh_m,
    const float* __restrict__ sa_i, const float* __restrict__ qa_i,
    const float* __restrict__ sa_j, const float* __restrict__ qa_j,
    const float* __restrict__ sqh,
    const float* __restrict__ ln_g, const float* __restrict__ ln_b,
    const float* __restrict__ s_w2, const float* __restrict__ s_b2,
    const float* __restrict__ gnn_w,
    float* __restrict__ h_res)
{
    int bi0 = blockIdx.x * 4;          // first row (b*256 + i0)
    int b   = bi0 >> 8;
    int j   = threadIdx.x;
    int gj  = b*256 + j;

    __shared__ float aiT[64][4], hiT[64][4];   // [d][i]
    __shared__ float gbw[64][4];               // {ln_g, ln_b, s_w2, 0}
    __shared__ float sai_s[4], qai_s[4], sqi_s[4];
    __shared__ float adj_sh[256][4];           // [j][i]
    __shared__ float pool[16*4*64];            // agg partials [16][4][64]
    __shared__ float hagg_sh[4][64];

    {
        int i = j >> 6, d = j & 63;
        aiT[d][i] = a_i[(bi0+i)*64 + d];
        hiT[d][i] = h[(bi0+i)*64 + d];
    }
    if (j < 64) {
        gbw[j][0] = ln_g[j]; gbw[j][1] = ln_b[j]; gbw[j][2] = s_w2[j]; gbw[j][3] = 0.f;
    }
    if (j < 4) {
        sai_s[j] = sa_i[bi0+j]; qai_s[j] = qa_i[bi0+j]; sqi_s[j] = sqh[bi0+j];
    }
    float saj = sa_j[gj], qaj = qa_j[gj], sqj = sqh[gj];
    float b2  = s_b2[0];
    float gav[4], ghv[4];
    #pragma unroll
    for (int i = 0; i < 4; ++i) {
        gav[i] = ga_m[(bi0+i)*256 + j];        // coalesced
        ghv[i] = gh_m[(bi0+i)*256 + j];
    }
    __syncthreads();

    const float2* ajhb = ajh + b*16384;        // [d][j] of {a_j, h}

    // ---- LN stats from scalar decomposition (grams precomputed) ----
    float rs4[4], nr4[4], d24[4];
    #pragma unroll
    for (int i = 0; i < 4; ++i) {
        float mu  = (sai_s[i] + saj) * (1.f/64.f);
        float pss = qai_s[i] + qaj + 2.f*gav[i];
        float var = pss * (1.f/64.f) - mu*mu;
        rs4[i] = frsq(var + 1e-5f);
        nr4[i] = -mu * rs4[i];
        d24[i] = fmaxf(sqi_s[i] + sqj - 2.f*ghv[i], 0.f);
    }

    // ---- pass 2: LN -> relu -> dot(w2) (single float2 stream) ----
    float acc[4] = {0.f,0.f,0.f,0.f};
    #pragma unroll 8
    for (int d = 0; d < 64; ++d) {
        float ajd = ajhb[d*256 + j].x;
        float4 A = *(const float4*)&aiT[d][0];
        float4 G = *(const float4*)&gbw[d][0];
        float t0 = fmaxf(fmaf(fmaf(A.x + ajd, rs4[0], nr4[0]), G.x, G.y), 0.f);
        acc[0] = fmaf(t0, G.z, acc[0]);
        float t1 = fmaxf(fmaf(fmaf(A.y + ajd, rs4[1], nr4[1]), G.x, G.y), 0.f);
        acc[1] = fmaf(t1, G.z, acc[1]);
        float t2 = fmaxf(fmaf(fmaf(A.z + ajd, rs4[2], nr4[2]), G.x, G.y), 0.f);
        acc[2] = fmaf(t2, G.z, acc[2]);
        float t3 = fmaxf(fmaf(fmaf(A.w + ajd, rs4[3], nr4[3]), G.x, G.y), 0.f);
        acc[3] = fmaf(t3, G.z, acc[3]);
    }

    // ---- sigma, adj ----
    {
        float4 av;
        #pragma unroll
        for (int i = 0; i < 4; ++i) {
            float sig = softplus_f(acc[i] + b2);
            float inv = frcp(2.f*sig*sig + 1e-6f);
            ((float*)&av)[i] = fexp(-d24[i] * inv);
        }
        *(float4*)&adj_sh[j][0] = av;
    }
    __syncthreads();

    // ---- aggregation: float4 loads, 16-lane-group mapping ----
    {
        int q = j >> 4, dq = j & 15;
        const float* hb = h + b*256*64;
        float4 p0 = {0.f,0.f,0.f,0.f}, p1 = p0, p2 = p0, p3 = p0;
        #pragma unroll
        for (int k = 0; k < 16; ++k) {
            int jj = q*16 + k;
            float4 hv = *(const float4*)&hb[jj*64 + dq*4];
            float4 a4 = *(const float4*)&adj_sh[jj][0];
            p0.x=fmaf(a4.x,hv.x,p0.x); p0.y=fmaf(a4.x,hv.y,p0.y);
            p0.z=fmaf(a4.x,hv.z,p0.z); p0.w=fmaf(a4.x,hv.w,p0.w);
            p1.x=fmaf(a4.y,hv.x,p1.x); p1.y=fmaf(a4.y,hv.y,p1.y);
            p1.z=fmaf(a4.y,hv.z,p1.z); p1.w=fmaf(a4.y,hv.w,p1.w);
            p2.x=fmaf(a4.z,hv.x,p2.x); p2.y=fmaf(a4.z,hv.y,p2.y);
            p2.z=fmaf(a4.z,hv.z,p2.z); p2.w=fmaf(a4.z,hv.w,p2.w);
            p3.x=fmaf(a4.w,hv.x,p3.x); p3.y=fmaf(a4.w,hv.y,p3.y);
            p3.z=fmaf(a4.w,hv.z,p3.z); p3.w=fmaf(a4.w,hv.w,p3.w);
        }
        *(float4*)&pool[(q*4 + 0)*64 + dq*4] = p0;
        *(float4*)&pool[(q*4 + 1)*64 + dq*4] = p1;
        *(float4*)&pool[(q*4 + 2)*64 + dq*4] = p2;
        *(float4*)&pool[(q*4 + 3)*64 + dq*4] = p3;
    }
    __syncthreads();

    {
        int i = j >> 6, d = j & 63;
        float s = 0.f;
        #pragma unroll
        for (int q2 = 0; q2 < 16; ++q2)
            s += pool[(q2*4 + i)*64 + d];
        hagg_sh[i][d] = s;
    }
    __syncthreads();

    // ---- fused gnn: h_res = elu(hagg @ gnn_w + h) ----
    {
        int i = j >> 6, lane = j & 63;
        float accg = 0.f;
        #pragma unroll 8
        for (int e = 0; e < 64; ++e)
            accg = fmaf(hagg_sh[i][e], gnn_w[e*64 + lane], accg);
        h_res[(bi0+i)*64 + lane] = elu_f(accg + hiT[lane][i]);
    }
}

// K4: pooled = [mean_i, max_i]; classifier.  16 blocks x 256 threads.
__global__ __launch_bounds__(256) void k4_pool_cls(
    const float* __restrict__ h_res,
    const float* __restrict__ c_w1, const float* __restrict__ c_b1,
    const float* __restrict__ bn_g, const float* __restrict__ bn_b,
    const float* __restrict__ bn_mean, const float* __restrict__ bn_var,
    const float* __restrict__ c_w2, const float* __restrict__ c_b2,
    float* __restrict__ out)
{
    int b = blockIdx.x;
    int tid = threadIdx.x;
    int d = tid & 63, q = tid >> 6;
    const float* hb = h_res + b*256*64;

    float sum = 0.f, mx = -INFINITY;
    #pragma unroll 8
    for (int k = 0; k < 64; ++k) {
        float v = hb[(q*64+k)*64 + d];
        sum += v; mx = fmaxf(mx, v);
    }
    __shared__ float sum_sh[256], max_sh[256];
    __shared__ float pm_sh[64], px_sh[64];
    sum_sh[tid] = sum; max_sh[tid] = mx;
    __syncthreads();
    if (tid < 64) {
        float tsum = sum_sh[tid] + sum_sh[64+tid] + sum_sh[128+tid] + sum_sh[192+tid];
        float tmax = fmaxf(fmaxf(max_sh[tid], max_sh[64+tid]),
                           fmaxf(max_sh[128+tid], max_sh[192+tid]));
        pm_sh[tid] = tsum * (1.f/256.f);
        px_sh[tid] = tmax;
    }
    __syncthreads();
    if (tid < 64) {
        float acc = c_b1[tid];
        #pragma unroll
        for (int e = 0; e < 64; ++e) {
            acc += pm_sh[e] * c_w1[e*64 + tid];
            acc += px_sh[e] * c_w1[(64+e)*64 + tid];
        }
        float z = (acc - bn_mean[tid]) * rsqrtf(bn_var[tid] + 1e-5f) * bn_g[tid] + bn_b[tid];
        z = elu_f(z);
        float c0 = z * c_w2[tid*2 + 0];
        float c1 = z * c_w2[tid*2 + 1];
        for (int off = 32; off > 0; off >>= 1) {
            c0 += __shfl_down(c0, off);
            c1 += __shfl_down(c1, off);
        }
        if (tid == 0) {
            out[b*2 + 0] = c0 + c_b2[0];
            out[b*2 + 1] = c1 + c_b2[1];
        }
    }
}

extern "C" void kernel_launch(void* const* d_in, const int* in_sizes, int n_in,
                              void* d_out, int out_size, void* d_ws, size_t ws_size,
                              hipStream_t stream) {
    const float* x       = (const float*)d_in[0];
    const float* proj_w  = (const float*)d_in[1];
    const float* proj_b  = (const float*)d_in[2];
    const float* s_w1    = (const float*)d_in[3];
    const float* s_b1    = (const float*)d_in[4];
    const float* ln_g    = (const float*)d_in[5];
    const float* ln_b    = (const float*)d_in[6];
    const float* s_w2    = (const float*)d_in[7];
    const float* s_b2    = (const float*)d_in[8];
    const float* gnn_w   = (const float*)d_in[9];
    const float* c_w1    = (const float*)d_in[10];
    const float* c_b1    = (const float*)d_in[11];
    const float* bn_g    = (const float*)d_in[12];
    const float* bn_b    = (const float*)d_in[13];
    const float* bn_mean = (const float*)d_in[14];
    const float* bn_var  = (const float*)d_in[15];
    const float* c_w2    = (const float*)d_in[16];
    const float* c_b2    = (const float*)d_in[17];

    float* w = (float*)d_ws;
    float*  h     = w + OFF_H;
    float*  a_i   = w + OFF_AI;
    float2* ajh   = (float2*)(w + OFF_AJH);
    float*  sa_i  = w + OFF_SAI;
    float*  qa_i  = w + OFF_QAI;
    float*  sa_j  = w + OFF_SAJ;
    float*  qa_j  = w + OFF_QAJ;
    float*  sqh   = w + OFF_SQH;
    float*  ga    = w + OFF_GA;
    float*  gh    = w + OFF_GH;
    float*  h_res = w + OFF_HRES;
    short*  ai_bf = (short*)(w + OFF_BF);
    short*  aj_bf = ai_bf + 262144;
    short*  h_bf  = ai_bf + 524288;
    float*  out   = (float*)d_out;

    k1_embed<<<512, 256, 0, stream>>>(x, proj_w, proj_b, s_w1, s_b1,
                                      h, a_i, ajh, ai_bf, aj_bf, h_bf,
                                      sa_i, qa_i, sa_j, qa_j, sqh);
    kgram<<<512, 64, 0, stream>>>(ai_bf, aj_bf, h_bf, ga, gh);
    k2_pair<<<1024, 256, 0, stream>>>(a_i, ajh, h, ga, gh,
                                      sa_i, qa_i, sa_j, qa_j, sqh,
                                      ln_g, ln_b, s_w2, s_b2, gnn_w, h_res);
    k4_pool_cls<<<16, 256, 0, stream>>>(h_res, c_w1, c_b1, bn_g, bn_b,
                                        bn_mean, bn_var, c_w2, c_b2, out);
}

// Round 20
// 46.123 us; speedup vs baseline: 2.6602x; 1.0238x over previous
//
#include <hip/hip_runtime.h>
#include <math.h>

// FinalGNN: b=16, n=256, feature=64
// ws layout (floats):
#define OFF_H      0                    // h    [4096][64] row-major
#define OFF_AI     262144               // a_i  [4096][64] (includes s_b1)
#define OFF_AJH    524288               // ajh  [16][64][256][2]  {a_j, h} interleaved
#define OFF_SAI    1048576              // per-row scalars, 4096 each
#define OFF_QAI    1052672
#define OFF_SAJ    1056768
#define OFF_QAJ    1060864
#define OFF_SQH    1064960
#define OFF_HRES   1069056              // h_res [4096][64]

// fast transcendentals (native HW exp/log; ~2-4 ulp, fine vs 5.25e-2 threshold)
__device__ __forceinline__ float fexp(float x)  { return __expf(x); }
__device__ __forceinline__ float flog(float x)  { return __logf(x); }
__device__ __forceinline__ float frcp(float x)  {
    float r = __builtin_amdgcn_rcpf(x);
    return r * (2.f - x * r);            // 1 Newton step
}
__device__ __forceinline__ float frsq(float x)  { return __builtin_amdgcn_rsqf(x); }
__device__ __forceinline__ float elu_f(float x) { return x > 0.f ? x : fexp(x) - 1.f; }
__device__ __forceinline__ float softplus_f(float x) {
    return fmaxf(x, 0.f) + flog(1.f + fexp(-fabsf(x)));
}

// K1: h = elu(x@proj_w+proj_b); a_i = h@s_w1[:64]+s_b1; a_j = h@s_w1[64:];
// ajh interleaved {a_j, h} transposed; row scalars via butterfly. 512 blocks x 256.
__global__ __launch_bounds__(256) void k1_embed(
    const float* __restrict__ x,
    const float* __restrict__ proj_w, const float* __restrict__ proj_b,
    const float* __restrict__ s_w1, const float* __restrict__ s_b1,
    float* __restrict__ h, float* __restrict__ a_i, float2* __restrict__ ajh,
    float* __restrict__ sa_i, float* __restrict__ qa_i,
    float* __restrict__ sa_j, float* __restrict__ qa_j,
    float* __restrict__ sqh)
{
    __shared__ float w_sh[8192];   // s_w1 [128][64]
    int tid = threadIdx.x;
    #pragma unroll
    for (int r = 0; r < 8; ++r)
        *(float4*)&w_sh[(r*256 + tid)*4] = *(const float4*)&s_w1[(r*256 + tid)*4];
    __syncthreads();

    int lane = tid & 63;
    int wave = tid >> 6;
    int row0 = blockIdx.x * 8;

    float pw0 = proj_w[lane], pw1 = proj_w[64+lane], pw2 = proj_w[128+lane],
          pw3 = proj_w[192+lane], pb = proj_b[lane], b1 = s_b1[lane];

    #pragma unroll
    for (int r = 0; r < 2; ++r) {
        int row = row0 + wave*2 + r;          // b*256 + i
        int b = row >> 8, i = row & 255;
        float4 xv = *(const float4*)&x[row*4];
        float hv = elu_f(xv.x*pw0 + xv.y*pw1 + xv.z*pw2 + xv.w*pw3 + pb);

        float ai = b1, aj = 0.f;
        #pragma unroll 8
        for (int e = 0; e < 64; ++e) {
            float he = __shfl(hv, e);
            ai = fmaf(he, w_sh[e*64 + lane], ai);
            aj = fmaf(he, w_sh[(64+e)*64 + lane], aj);
        }
        h[row*64 + lane]   = hv;
        a_i[row*64 + lane] = ai;
        // ajh[b][d=lane][i] = {a_j, h}
        ajh[b*16384 + lane*256 + i] = make_float2(aj, hv);

        float v1 = ai, v2 = ai*ai, v3 = aj, v4 = aj*aj, v5 = hv*hv;
        #pragma unroll
        for (int off = 32; off > 0; off >>= 1) {
            v1 += __shfl_xor(v1, off);
            v2 += __shfl_xor(v2, off);
            v3 += __shfl_xor(v3, off);
            v4 += __shfl_xor(v4, off);
            v5 += __shfl_xor(v5, off);
        }
        if (lane == 0) {
            sa_i[row] = v1; qa_i[row] = v2;
            sa_j[row] = v3; qa_j[row] = v4;
            sqh[row]  = v5;
        }
    }
}

// K2: R15 structure + fast transcendentals.
// 1024 blocks x 256 threads; block = (b, 4-i tile), thread = j.
__global__ __launch_bounds__(256) void k2_pair(
    const float* __restrict__ a_i, const float2* __restrict__ ajh,
    const float* __restrict__ h,
    const float* __restrict__ sa_i, const float* __restrict__ qa_i,
    const float* __restrict__ sa_j, const float* __restrict__ qa_j,
    const float* __restrict__ sqh,
    const float* __restrict__ ln_g, const float* __restrict__ ln_b,
    const float* __restrict__ s_w2, const float* __restrict__ s_b2,
    const float* __restrict__ gnn_w,
    float* __restrict__ h_res)
{
    int bi0 = blockIdx.x * 4;          // first row (b*256 + i0)
    int b   = bi0 >> 8;
    int j   = threadIdx.x;
    int gj  = b*256 + j;

    __shared__ float aiT[64][4], hiT[64][4];   // [d][i]
    __shared__ float gbw[64][4];               // {ln_g, ln_b, s_w2, 0}
    __shared__ float sai_s[4], qai_s[4], sqi_s[4];
    __shared__ float adj_sh[256][4];           // [j][i]
    __shared__ float pool[16*4*64];            // agg partials [16][4][64]
    __shared__ float hagg_sh[4][64];

    {
        int i = j >> 6, d = j & 63;
        aiT[d][i] = a_i[(bi0+i)*64 + d];
        hiT[d][i] = h[(bi0+i)*64 + d];
    }
    if (j < 64) {
        gbw[j][0] = ln_g[j]; gbw[j][1] = ln_b[j]; gbw[j][2] = s_w2[j]; gbw[j][3] = 0.f;
    }
    if (j < 4) {
        sai_s[j] = sa_i[bi0+j]; qai_s[j] = qa_i[bi0+j]; sqi_s[j] = sqh[bi0+j];
    }
    float saj = sa_j[gj], qaj = qa_j[gj], sqj = sqh[gj];
    float b2  = s_b2[0];
    __syncthreads();

    const float2* ajhb = ajh + b*16384;        // [d][j] of {a_j, h}

    // ---- pass 1: grams from single float2 stream ----
    float ga[4] = {0.f,0.f,0.f,0.f}, gh[4] = {0.f,0.f,0.f,0.f};
    #pragma unroll 8
    for (int d = 0; d < 64; ++d) {
        float2 v = ajhb[d*256 + j];
        float4 A = *(const float4*)&aiT[d][0];
        float4 H = *(const float4*)&hiT[d][0];
        ga[0] = fmaf(A.x, v.x, ga[0]); ga[1] = fmaf(A.y, v.x, ga[1]);
        ga[2] = fmaf(A.z, v.x, ga[2]); ga[3] = fmaf(A.w, v.x, ga[3]);
        gh[0] = fmaf(H.x, v.y, gh[0]); gh[1] = fmaf(H.y, v.y, gh[1]);
        gh[2] = fmaf(H.z, v.y, gh[2]); gh[3] = fmaf(H.w, v.y, gh[3]);
    }

    // ---- LN stats from scalar decomposition (fast rsqrt) ----
    float rs4[4], nr4[4], d24[4];
    #pragma unroll
    for (int i = 0; i < 4; ++i) {
        float mu  = (sai_s[i] + saj) * (1.f/64.f);
        float pss = qai_s[i] + qaj + 2.f*ga[i];
        float var = pss * (1.f/64.f) - mu*mu;
        rs4[i] = frsq(var + 1e-5f);
        nr4[i] = -mu * rs4[i];
        d24[i] = fmaxf(sqi_s[i] + sqj - 2.f*gh[i], 0.f);
    }

    // ---- pass 2: reread float2 (L2-hot), LN -> relu -> dot(w2) ----
    float acc[4] = {0.f,0.f,0.f,0.f};
    #pragma unroll 8
    for (int d = 0; d < 64; ++d) {
        float ajd = ajhb[d*256 + j].x;
        float4 A = *(const float4*)&aiT[d][0];
        float4 G = *(const float4*)&gbw[d][0];
        float t0 = fmaxf(fmaf(fmaf(A.x + ajd, rs4[0], nr4[0]), G.x, G.y), 0.f);
        acc[0] = fmaf(t0, G.z, acc[0]);
        float t1 = fmaxf(fmaf(fmaf(A.y + ajd, rs4[1], nr4[1]), G.x, G.y), 0.f);
        acc[1] = fmaf(t1, G.z, acc[1]);
        float t2 = fmaxf(fmaf(fmaf(A.z + ajd, rs4[2], nr4[2]), G.x, G.y), 0.f);
        acc[2] = fmaf(t2, G.z, acc[2]);
        float t3 = fmaxf(fmaf(fmaf(A.w + ajd, rs4[3], nr4[3]), G.x, G.y), 0.f);
        acc[3] = fmaf(t3, G.z, acc[3]);
    }

    // ---- sigma, adj (fast exp/log/rcp) ----
    {
        float4 av;
        #pragma unroll
        for (int i = 0; i < 4; ++i) {
            float sig = softplus_f(acc[i] + b2);
            float inv = frcp(2.f*sig*sig + 1e-6f);
            ((float*)&av)[i] = fexp(-d24[i] * inv);
        }
        *(float4*)&adj_sh[j][0] = av;
    }
    __syncthreads();

    // ---- aggregation: float4 loads, 16-lane-group mapping ----
    {
        int q = j >> 4, dq = j & 15;
        const float* hb = h + b*256*64;
        float4 p0 = {0.f,0.f,0.f,0.f}, p1 = p0, p2 = p0, p3 = p0;
        #pragma unroll
        for (int k = 0; k < 16; ++k) {
            int jj = q*16 + k;
            float4 hv = *(const float4*)&hb[jj*64 + dq*4];
            float4 a4 = *(const float4*)&adj_sh[jj][0];
            p0.x=fmaf(a4.x,hv.x,p0.x); p0.y=fmaf(a4.x,hv.y,p0.y);
            p0.z=fmaf(a4.x,hv.z,p0.z); p0.w=fmaf(a4.x,hv.w,p0.w);
            p1.x=fmaf(a4.y,hv.x,p1.x); p1.y=fmaf(a4.y,hv.y,p1.y);
            p1.z=fmaf(a4.y,hv.z,p1.z); p1.w=fmaf(a4.y,hv.w,p1.w);
            p2.x=fmaf(a4.z,hv.x,p2.x); p2.y=fmaf(a4.z,hv.y,p2.y);
            p2.z=fmaf(a4.z,hv.z,p2.z); p2.w=fmaf(a4.z,hv.w,p2.w);
            p3.x=fmaf(a4.w,hv.x,p3.x); p3.y=fmaf(a4.w,hv.y,p3.y);
            p3.z=fmaf(a4.w,hv.z,p3.z); p3.w=fmaf(a4.w,hv.w,p3.w);
        }
        *(float4*)&pool[(q*4 + 0)*64 + dq*4] = p0;
        *(float4*)&pool[(q*4 + 1)*64 + dq*4] = p1;
        *(float4*)&pool[(q*4 + 2)*64 + dq*4] = p2;
        *(float4*)&pool[(q*4 + 3)*64 + dq*4] = p3;
    }
    __syncthreads();

    {
        int i = j >> 6, d = j & 63;
        float s = 0.f;
        #pragma unroll
        for (int q2 = 0; q2 < 16; ++q2)
            s += pool[(q2*4 + i)*64 + d];
        hagg_sh[i][d] = s;
    }
    __syncthreads();

    // ---- fused gnn: h_res = elu(hagg @ gnn_w + h) ----
    {
        int i = j >> 6, lane = j & 63;
        float accg = 0.f;
        #pragma unroll 8
        for (int e = 0; e < 64; ++e)
            accg = fmaf(hagg_sh[i][e], gnn_w[e*64 + lane], accg);
        h_res[(bi0+i)*64 + lane] = elu_f(accg + hiT[lane][i]);
    }
}

// K4: pooled = [mean_i, max_i]; classifier.  16 blocks x 256 threads.
__global__ __launch_bounds__(256) void k4_pool_cls(
    const float* __restrict__ h_res,
    const float* __restrict__ c_w1, const float* __restrict__ c_b1,
    const float* __restrict__ bn_g, const float* __restrict__ bn_b,
    const float* __restrict__ bn_mean, const float* __restrict__ bn_var,
    const float* __restrict__ c_w2, const float* __restrict__ c_b2,
    float* __restrict__ out)
{
    int b = blockIdx.x;
    int tid = threadIdx.x;
    int d = tid & 63, q = tid >> 6;
    const float* hb = h_res + b*256*64;

    float sum = 0.f, mx = -INFINITY;
    #pragma unroll 8
    for (int k = 0; k < 64; ++k) {
        float v = hb[(q*64+k)*64 + d];
        sum += v; mx = fmaxf(mx, v);
    }
    __shared__ float sum_sh[256], max_sh[256];
    __shared__ float pm_sh[64], px_sh[64];
    sum_sh[tid] = sum; max_sh[tid] = mx;
    __syncthreads();
    if (tid < 64) {
        float tsum = sum_sh[tid] + sum_sh[64+tid] + sum_sh[128+tid] + sum_sh[192+tid];
        float tmax = fmaxf(fmaxf(max_sh[tid], max_sh[64+tid]),
                           fmaxf(max_sh[128+tid], max_sh[192+tid]));
        pm_sh[tid] = tsum * (1.f/256.f);
        px_sh[tid] = tmax;
    }
    __syncthreads();
    if (tid < 64) {
        float acc = c_b1[tid];
        #pragma unroll
        for (int e = 0; e < 64; ++e) {
            acc += pm_sh[e] * c_w1[e*64 + tid];
            acc += px_sh[e] * c_w1[(64+e)*64 + tid];
        }
        float z = (acc - bn_mean[tid]) * rsqrtf(bn_var[tid] + 1e-5f) * bn_g[tid] + bn_b[tid];
        z = elu_f(z);
        float c0 = z * c_w2[tid*2 + 0];
        float c1 = z * c_w2[tid*2 + 1];
        for (int off = 32; off > 0; off >>= 1) {
            c0 += __shfl_down(c0, off);
            c1 += __shfl_down(c1, off);
        }
        if (tid == 0) {
            out[b*2 + 0] = c0 + c_b2[0];
            out[b*2 + 1] = c1 + c_b2[1];
        }
    }
}

extern "C" void kernel_launch(void* const* d_in, const int* in_sizes, int n_in,
                              void* d_out, int out_size, void* d_ws, size_t ws_size,
                              hipStream_t stream) {
    const float* x       = (const float*)d_in[0];
    const float* proj_w  = (const float*)d_in[1];
    const float* proj_b  = (const float*)d_in[2];
    const float* s_w1    = (const float*)d_in[3];
    const float* s_b1    = (const float*)d_in[4];
    const float* ln_g    = (const float*)d_in[5];
    const float* ln_b    = (const float*)d_in[6];
    const float* s_w2    = (const float*)d_in[7];
    const float* s_b2    = (const float*)d_in[8];
    const float* gnn_w   = (const float*)d_in[9];
    const float* c_w1    = (const float*)d_in[10];
    const float* c_b1    = (const float*)d_in[11];
    const float* bn_g    = (const float*)d_in[12];
    const float* bn_b    = (const float*)d_in[13];
    const float* bn_mean = (const float*)d_in[14];
    const float* bn_var  = (const float*)d_in[15];
    const float* c_w2    = (const float*)d_in[16];
    const float* c_b2    = (const float*)d_in[17];

    float* w = (float*)d_ws;
    float*  h     = w + OFF_H;
    float*  a_i   = w + OFF_AI;
    float2* ajh   = (float2*)(w + OFF_AJH);
    float*  sa_i  = w + OFF_SAI;
    float*  qa_i  = w + OFF_QAI;
    float*  sa_j  = w + OFF_SAJ;
    float*  qa_j  = w + OFF_QAJ;
    float*  sqh   = w + OFF_SQH;
    float*  h_res = w + OFF_HRES;
    float*  out   = (float*)d_out;

    k1_embed<<<512, 256, 0, stream>>>(x, proj_w, proj_b, s_w1, s_b1,
                                      h, a_i, ajh,
                                      sa_i, qa_i, sa_j, qa_j, sqh);
    k2_pair<<<1024, 256, 0, stream>>>(a_i, ajh, h,
                                      sa_i, qa_i, sa_j, qa_j, sqh,
                                      ln_g, ln_b, s_w2, s_b2, gnn_w, h_res);
    k4_pool_cls<<<16, 256, 0, stream>>>(h_res, c_w1, c_b1, bn_g, bn_b,
                                        bn_mean, bn_var, c_w2, c_b2, out);
}